// Round 5
// baseline (202.456 us; speedup 1.0000x reference)
//
#include <hip/hip_runtime.h>

#define D 4096
#define DM 4095
#define BS 128   // bundle size
#define NROW 64  // B * nb = 4 * 16
#define JC 8     // corr K-chunks (512 m each)

#define ZSTR 520   // u16 stride of zsh rows (65 uint4-groups, ==1 mod 8)
#define PSTR 808   // u16 stride of parity rows (101 uint4-groups, ==5 mod 8)
#define PBLEN 4928 // bf16 ring length (>= 4095 + 808, 16B-multiple)

typedef __attribute__((ext_vector_type(8))) short bf16x8;
typedef __attribute__((ext_vector_type(4))) float f32x4;

// round-to-nearest-even f32 -> bf16 bits
__device__ __forceinline__ unsigned short f2bf(float f) {
  union { float f; unsigned int u; } v;
  v.f = f;
  const unsigned int r = v.u + 0x7fffu + ((v.u >> 16) & 1u);
  return (unsigned short)(r >> 16);
}

__device__ __forceinline__ float bf2f(unsigned short h) {
  union { unsigned int u; float f; } v;
  v.u = (unsigned int)h << 16;
  return v.f;
}

// ---------- kernel 1: fused softmax + shifted weighted sum -> bf16 z --------
// z[row][m] = sum_{s=0..127} softmax(pw)[s] * tok[row][s][(m+s)%D]
// 512-thread blocks cover a 256-group output window (2 old mc windows):
// halo overlap between blocks drops from 25% to 12.5% of the read set.
// Block (0,0) additionally materializes 8 parity-shifted bf16 base rings:
//   pbp[p][y] = bf16(base[(p + y) & DM]),  y in [0, PBLEN)
__global__ __launch_bounds__(512) void zshift_k(const float* __restrict__ tok,
                                                const float* __restrict__ pw,
                                                const float* __restrict__ base,
                                                unsigned short* __restrict__ zb,
                                                unsigned short* __restrict__ pbp) {
  const int t = threadIdx.x;
  const int mc = blockIdx.x;   // 0..3
  const int row = blockIdx.y;  // 0..63

  if (mc == 0 && row == 0) {
    for (int x = t; x < PBLEN; x += 512) {
#pragma unroll
      for (int p = 0; p < 8; ++p)
        pbp[p * PBLEN + x] = f2bf(base[(p + x) & DM]);
    }
  }

  __shared__ float wsh[BS];
  __shared__ float red[8];
  __shared__ float4 xsh[256];
  {
    const float v = (t < BS) ? pw[t] : -1e30f;
    float m = v;
#pragma unroll
    for (int o = 32; o > 0; o >>= 1) m = fmaxf(m, __shfl_xor(m, o));
    if ((t & 63) == 0) red[t >> 6] = m;
    __syncthreads();
    m = red[0];
#pragma unroll
    for (int i = 1; i < 8; ++i) m = fmaxf(m, red[i]);
    const float e = (t < BS) ? expf(v - m) : 0.f;
    float s = e;
#pragma unroll
    for (int o = 32; o > 0; o >>= 1) s += __shfl_xor(s, o);
    __syncthreads();
    if ((t & 63) == 0) red[t >> 6] = s;
    __syncthreads();
    s = 0.f;
#pragma unroll
    for (int i = 0; i < 8; ++i) s += red[i];
    if (t < BS) wsh[t] = e / s;
    __syncthreads();
  }

  const int g = t & 255;        // local output group
  const int h = t >> 8;         // s-half (wave-uniform)
  const int og = (mc << 8) + g; // global output group (4 floats)
  const float4* tr = (const float4*)(tok + (size_t)row * (BS * D));

  float4 acc = make_float4(0.f, 0.f, 0.f, 0.f);
#pragma unroll
  for (int qq = 0; qq < 16; ++qq) {
    const int q = (h << 4) + qq;   // s-quad, s = 4q + r
    const float w0 = wsh[4 * q + 0], w1 = wsh[4 * q + 1];
    const float w2 = wsh[4 * q + 2], w3 = wsh[4 * q + 3];
    const int G = (og + q) & 1023;
    const int G1 = (G + 1) & 1023;
    const size_t r0 = (size_t)(4 * q + 0) << 10;
    const size_t r1 = (size_t)(4 * q + 1) << 10;
    const size_t r2 = (size_t)(4 * q + 2) << 10;
    const size_t r3 = (size_t)(4 * q + 3) << 10;
    const float4 a0 = tr[r0 + G];
    const float4 a1 = tr[r1 + G], b1 = tr[r1 + G1];
    const float4 a2 = tr[r2 + G], b2 = tr[r2 + G1];
    const float4 a3 = tr[r3 + G], b3 = tr[r3 + G1];
    acc.x += w0 * a0.x; acc.y += w0 * a0.y;
    acc.z += w0 * a0.z; acc.w += w0 * a0.w;
    acc.x += w1 * a1.y; acc.y += w1 * a1.z;
    acc.z += w1 * a1.w; acc.w += w1 * b1.x;
    acc.x += w2 * a2.z; acc.y += w2 * a2.w;
    acc.z += w2 * b2.x; acc.w += w2 * b2.y;
    acc.x += w3 * a3.w; acc.y += w3 * b3.x;
    acc.z += w3 * b3.y; acc.w += w3 * b3.z;
  }
  if (h) xsh[g] = acc;
  __syncthreads();
  if (!h) {
    const float4 o = xsh[g];
    ushort4 u;
    u.x = f2bf(acc.x + o.x);
    u.y = f2bf(acc.y + o.y);
    u.z = f2bf(acc.z + o.z);
    u.w = f2bf(acc.w + o.w);
    *(ushort4*)(zb + (size_t)row * D + ((size_t)og << 2)) = u;
  }
}

// ---------- kernel 2: circulant matmul via bf16 MFMA ------------------------
// braw[jc][row][d] = bf16( sum_{m in chunk} z[row][m] * base[(m-d)%D] )
// C^T formulation: M=d (A = circulant), N=row (B = z), K=m.
// Each block: 4 consecutive 64-d tiles x 32 rows. psh (row-independent) is
// reused across both 16-row groups; B-fragments reused by 4 MFMAs (d-batch),
// A-fragments reused by 2 MFMAs (row-batch): 6 ds_reads per 8 MFMAs.
__global__ __launch_bounds__(256) void corr_k(const unsigned short* __restrict__ zb,
                                              const unsigned short* __restrict__ pbp,
                                              unsigned short* __restrict__ braw) {
  __shared__ __align__(16) unsigned short zsh[32 * ZSTR];  // 32 rows x 512 bf16
  __shared__ __align__(16) unsigned short psh[8 * PSTR];   // 8 parity rows x 808
  const int t = threadIdx.x;
  const int jc = blockIdx.x;   // 0..7   K-chunk
  const int dgq = blockIdx.y;  // 0..15  256 d's per block (4 x 64)
  const int rth = blockIdx.z;  // 0..1   32 rows per block
  const int jb = jc << 9;
  const int dqb = dgq << 8;    // d base of the 4-tile group

  // stage zsh: 32 rows x 512 bf16; thread (rr = t>>3) writes 64 u16 at (t&7)*64
  // (8 uint4 copies — full coverage of the 64-u16 stripe)
  {
    const int rr = t >> 3;
    const int c0 = (t & 7) << 6;
    const uint4* src =
        (const uint4*)(zb + (size_t)(rth * 32 + rr) * D + jb + c0);
    uint4* dst = (uint4*)(zsh + rr * ZSTR + c0);
#pragma unroll
    for (int x = 0; x < 8; ++x) dst[x] = src[x];
  }
  // stage parity rows from the 8 shifted rings — fully 16B-aligned:
  // psh[r][x] = base[(s_lo + r + x) & DM], s_lo = (jb - dqb - 256) mod D
  //           = pbp[sr&7][(sr - (sr&7)) + x],  sr = (s_lo + r) & DM
  {
    const int r = t >> 5;       // 0..7
    const int x0 = t & 31;
    const int sr = (jb - dqb - 256 + 2 * D + r) & DM;
    const int p = sr & 7;
    const uint4* src = (const uint4*)(pbp + p * PBLEN + (sr - p));
    uint4* dst = (uint4*)(psh + r * PSTR);
#pragma unroll
    for (int x = x0; x < 101; x += 32) dst[x] = src[x];
  }
  __syncthreads();

  const int lane = t & 63;
  const int w = t >> 6;        // wave id: d-subtile within each 64-d tile
  const int dd = lane & 15;    // A: m-index (d offset); B: n-index (row offset)
  const int q = lane >> 4;     // k = 8q + j
  // A window start for dgi=3 (in-psh offset 0): a0 = 64 + 8q - 16w - dd, [1,88]
  // dgi adds 64*(3-dgi) u16 (multiple of 64 -> parity pr invariant).
  const int a0 = 64 + (q << 3) - (w << 4) - dd;
  const int pr = a0 & 7;
  const int px = a0 - pr;      // multiple of 8 -> 16B aligned
  const unsigned short* pA = psh + pr * PSTR + px;
  const unsigned short* pB0 = zsh + dd * ZSTR + (q << 3);
  const unsigned short* pB1 = zsh + (16 + dd) * ZSTR + (q << 3);

  f32x4 a0r0 = {0.f, 0.f, 0.f, 0.f};  // dgi=0 (pA offset +192), rows 0..15
  f32x4 a1r0 = {0.f, 0.f, 0.f, 0.f};
  f32x4 a2r0 = {0.f, 0.f, 0.f, 0.f};
  f32x4 a3r0 = {0.f, 0.f, 0.f, 0.f};  // dgi=3 (+0)
  f32x4 a0r1 = {0.f, 0.f, 0.f, 0.f};  // rows 16..31
  f32x4 a1r1 = {0.f, 0.f, 0.f, 0.f};
  f32x4 a2r1 = {0.f, 0.f, 0.f, 0.f};
  f32x4 a3r1 = {0.f, 0.f, 0.f, 0.f};
#pragma unroll
  for (int ks = 0; ks < 16; ++ks) {
    const bf16x8 bfa = *(const bf16x8*)(pB0 + (ks << 5));
    const bf16x8 bfb = *(const bf16x8*)(pB1 + (ks << 5));
    const bf16x8 af3 = *(const bf16x8*)(pA + (ks << 5));
    const bf16x8 af2 = *(const bf16x8*)(pA + 64 + (ks << 5));
    const bf16x8 af1 = *(const bf16x8*)(pA + 128 + (ks << 5));
    const bf16x8 af0 = *(const bf16x8*)(pA + 192 + (ks << 5));
    a3r0 = __builtin_amdgcn_mfma_f32_16x16x32_bf16(af3, bfa, a3r0, 0, 0, 0);
    a2r0 = __builtin_amdgcn_mfma_f32_16x16x32_bf16(af2, bfa, a2r0, 0, 0, 0);
    a1r0 = __builtin_amdgcn_mfma_f32_16x16x32_bf16(af1, bfa, a1r0, 0, 0, 0);
    a0r0 = __builtin_amdgcn_mfma_f32_16x16x32_bf16(af0, bfa, a0r0, 0, 0, 0);
    a3r1 = __builtin_amdgcn_mfma_f32_16x16x32_bf16(af3, bfb, a3r1, 0, 0, 0);
    a2r1 = __builtin_amdgcn_mfma_f32_16x16x32_bf16(af2, bfb, a2r1, 0, 0, 0);
    a1r1 = __builtin_amdgcn_mfma_f32_16x16x32_bf16(af1, bfb, a1r1, 0, 0, 0);
    a0r1 = __builtin_amdgcn_mfma_f32_16x16x32_bf16(af0, bfb, a0r1, 0, 0, 0);
  }
  // D: col(n)=lane&15 -> output row; row(m)=quad*4+reg -> d index
  const int row0 = rth * 32 + dd;
  const int row1 = rth * 32 + 16 + dd;
  const size_t rb0 = (size_t)(jc * NROW + row0) * D;
  const size_t rb1 = (size_t)(jc * NROW + row1) * D;
  const int dloc = (w << 4) + (q << 2);
  ushort4 u;
  u.x = f2bf(a0r0[0]); u.y = f2bf(a0r0[1]);
  u.z = f2bf(a0r0[2]); u.w = f2bf(a0r0[3]);
  *(ushort4*)(braw + rb0 + dqb + 0 + dloc) = u;
  u.x = f2bf(a1r0[0]); u.y = f2bf(a1r0[1]);
  u.z = f2bf(a1r0[2]); u.w = f2bf(a1r0[3]);
  *(ushort4*)(braw + rb0 + dqb + 64 + dloc) = u;
  u.x = f2bf(a2r0[0]); u.y = f2bf(a2r0[1]);
  u.z = f2bf(a2r0[2]); u.w = f2bf(a2r0[3]);
  *(ushort4*)(braw + rb0 + dqb + 128 + dloc) = u;
  u.x = f2bf(a3r0[0]); u.y = f2bf(a3r0[1]);
  u.z = f2bf(a3r0[2]); u.w = f2bf(a3r0[3]);
  *(ushort4*)(braw + rb0 + dqb + 192 + dloc) = u;
  u.x = f2bf(a0r1[0]); u.y = f2bf(a0r1[1]);
  u.z = f2bf(a0r1[2]); u.w = f2bf(a0r1[3]);
  *(ushort4*)(braw + rb1 + dqb + 0 + dloc) = u;
  u.x = f2bf(a1r1[0]); u.y = f2bf(a1r1[1]);
  u.z = f2bf(a1r1[2]); u.w = f2bf(a1r1[3]);
  *(ushort4*)(braw + rb1 + dqb + 64 + dloc) = u;
  u.x = f2bf(a2r1[0]); u.y = f2bf(a2r1[1]);
  u.z = f2bf(a2r1[2]); u.w = f2bf(a2r1[3]);
  *(ushort4*)(braw + rb1 + dqb + 128 + dloc) = u;
  u.x = f2bf(a3r1[0]); u.y = f2bf(a3r1[1]);
  u.z = f2bf(a3r1[2]); u.w = f2bf(a3r1[3]);
  *(ushort4*)(braw + rb1 + dqb + 192 + dloc) = u;
}

// ---------- kernel 3: sum K-chunk partials + L2 normalize -------------------
__global__ __launch_bounds__(1024) void norm_k(const unsigned short* __restrict__ braw,
                                               float* __restrict__ out) {
  const int t = threadIdx.x;
  const int row = blockIdx.x;
  float4 s = make_float4(0.f, 0.f, 0.f, 0.f);
#pragma unroll
  for (int p = 0; p < JC; ++p) {
    const ushort4 v = *(const ushort4*)(braw +
        (size_t)(p * NROW + row) * D + (t << 2));
    s.x += bf2f(v.x); s.y += bf2f(v.y); s.z += bf2f(v.z); s.w += bf2f(v.w);
  }
  float ssq = s.x * s.x + s.y * s.y + s.z * s.z + s.w * s.w;
#pragma unroll
  for (int o = 32; o > 0; o >>= 1) ssq += __shfl_xor(ssq, o);
  __shared__ float red[16];
  if ((t & 63) == 0) red[t >> 6] = ssq;
  __syncthreads();
  float tot = 0.f;
#pragma unroll
  for (int i = 0; i < 16; ++i) tot += red[i];
  const float sc = rsqrtf(fmaxf(tot, 1e-8f));
  float4 o;
  o.x = s.x * sc; o.y = s.y * sc; o.z = s.z * sc; o.w = s.w * sc;
  ((float4*)out)[(size_t)row * (D / 4) + t] = o;
}

extern "C" void kernel_launch(void* const* d_in, const int* in_sizes, int n_in,
                              void* d_out, int out_size, void* d_ws, size_t ws_size,
                              hipStream_t stream) {
  (void)in_sizes; (void)n_in; (void)out_size; (void)ws_size;
  const float* tok = (const float*)d_in[0];   // [4,2048,4096] f32
  const float* base = (const float*)d_in[1];  // [4096] f32
  const float* pw = (const float*)d_in[2];    // [128] f32
  float* out = (float*)d_out;                 // [64,4096] f32

  unsigned short* zb = (unsigned short*)d_ws;          // 64*4096 bf16 (512 KB)
  unsigned short* pbp = zb + (size_t)NROW * D;         // 8*PBLEN bf16 (~77 KB)
  unsigned short* braw = pbp + 8 * PBLEN;              // JC*64*4096 bf16 (4 MB)

  zshift_k<<<dim3(4, NROW), 512, 0, stream>>>(tok, pw, base, zb, pbp);
  corr_k<<<dim3(JC, 16, 2), 256, 0, stream>>>(zb, pbp, braw);
  norm_k<<<NROW, 1024, 0, stream>>>(braw, out);
}